// Round 14
// baseline (1686.099 us; speedup 1.0000x reference)
//
#include <hip/hip_runtime.h>

// InteractionGNN on MI355X — Round 14: register double-buffered K-loop.
// R13 post-mortem: barrier-free loop is memory-LATENCY bound (MfmaUtil 15%,
// VGPR=88 -> compiler did not pipeline; each chunk stalls on its own loads).
// This round: explicit ping-pong register prefetch — chunk ch+1's 8 frags are
// issued before chunk ch's 16 MFMAs. Everything else identical to R13.

#define TPB 256
constexpr int D    = 128;
constexpr int NN   = 100000;
constexpr int NE   = 600000;

typedef unsigned short u16;
typedef __attribute__((ext_vector_type(8))) short bf16x8;
typedef __attribute__((ext_vector_type(4))) float f32x4;

__device__ inline float bf2f(u16 x) { return __uint_as_float((unsigned)x << 16); }
__device__ inline u16 f2bf(float f) {   // round-to-nearest-even
    unsigned u = __float_as_uint(f);
    unsigned r = u + 0x7FFFu + ((u >> 16) & 1u);
    return (u16)(r >> 16);
}
__device__ inline int load_idx(const int* ei, long pos, int is64) {
    int v = is64 ? ei[2 * pos] : ei[pos];
    return (v < 0) ? 0 : (v >= NN ? NN - 1 : v);
}
__device__ inline bf16x8 pack8(float4 f0, float4 f1) {
    union { bf16x8 v; u16 t[8]; } u;
    u.t[0] = f2bf(f0.x); u.t[1] = f2bf(f0.y); u.t[2] = f2bf(f0.z); u.t[3] = f2bf(f0.w);
    u.t[4] = f2bf(f1.x); u.t[5] = f2bf(f1.y); u.t[6] = f2bf(f1.z); u.t[7] = f2bf(f1.w);
    return u.v;
}
__device__ inline bf16x8 zero8() {
    union { bf16x8 v; u16 t[8]; } u;
    #pragma unroll
    for (int j = 0; j < 8; ++j) u.t[j] = 0;
    return u.v;
}

// ---------------------------------------------------------------------------
// Register-pipelined MFMA MLP. Block tile 128x128; 4 waves 2x2; wave 64x64.
// MODE: 0 node-enc (K=32 pad, fin fp32[*,16]) | 1 edge-enc (K=256, [h_s,h_t])
//       2 node-upd (K=256, [h, msg fp32], +h) | 3 edge-upd (K=384, [h_s,h_t,e], +e)
//       4 decoder  (K=384, layer2 128->1, fp32 out)
// W1f/W2f frag-major bf16: idx = ((ch*2+wn)*4+nt)*512 + lane*8.
// ---------------------------------------------------------------------------
template<int K, int MODE>
__device__ inline void mfma2(const u16* hbuf, const u16* ebuf, const float* fin,
                             const int* ei, const int* idxFlag,
                             const u16* __restrict__ W1f, const float* b1,
                             const u16* __restrict__ W2f, const float* w2orb2,
                             const float* bias2, void* outp)
{
    constexpr int NCH = K / 32;
    constexpr long NROWS = (MODE == 0 || MODE == 2) ? NN : NE;

    __shared__ alignas(16) u16 Hs[128 * 136];   // 34.8 KB
    __shared__ int   sIdx[128];
    __shared__ int   tIdx[128];
    __shared__ float part[256];
    __shared__ float w2s[128];

    const int tid  = threadIdx.x;
    const int lane = tid & 63;
    const int wave = tid >> 6;
    const int wm   = wave >> 1;
    const int wn   = wave & 1;
    const int lr   = lane & 15;
    const int lq   = lane >> 4;
    const long tile0 = (long)blockIdx.x * 128;

    if (MODE == 1 || MODE == 3 || MODE == 4) {
        const int is64 = idxFlag[0];
        if (tid < 128) {
            long p = tile0 + tid; if (p > NE - 1) p = NE - 1;
            sIdx[tid] = load_idx(ei, p, is64);
        } else {
            int r = tid - 128;
            long p = tile0 + r; if (p > NE - 1) p = NE - 1;
            tIdx[r] = load_idx(ei, (long)NE + p, is64);
        }
        if (MODE == 4 && tid < 128) w2s[tid] = w2orb2[tid];
        __syncthreads();
    } else if (MODE == 4) {
        if (tid < 128) w2s[tid] = w2orb2[tid];
    }

    // per-lane row constants
    long grow[4]; int si[4], ti[4];
    #pragma unroll
    for (int mt = 0; mt < 4; ++mt) {
        int rloc = wm * 64 + mt * 16 + lr;
        long g = tile0 + rloc; if (g > NROWS - 1) g = NROWS - 1;
        grow[mt] = g;
        if (MODE == 1 || MODE == 3 || MODE == 4) { si[mt] = sIdx[rloc]; ti[mt] = tIdx[rloc]; }
    }

    // fragment loaders (ch resolves to a constant after full unroll)
    auto loadA = [&](int ch, bf16x8 (&a)[4]) {
        const int k = ch * 32 + lq * 8;
        #pragma unroll
        for (int mt = 0; mt < 4; ++mt) {
            if (MODE == 0) {
                if (lq < 2) {
                    const float* s = &fin[grow[mt] * 16 + lq * 8];
                    a[mt] = pack8(*(const float4*)s, *(const float4*)(s + 4));
                } else a[mt] = zero8();
            } else if (MODE == 1) {
                const u16* s = (k < 128) ? &hbuf[(long)si[mt] * 128 + k]
                                         : &hbuf[(long)ti[mt] * 128 + (k - 128)];
                a[mt] = *(const bf16x8*)s;
            } else if (MODE == 2) {
                if (k < 128) {
                    a[mt] = *(const bf16x8*)&hbuf[grow[mt] * 128 + k];
                } else {
                    const float* s = &fin[grow[mt] * 128 + (k - 128)];
                    a[mt] = pack8(*(const float4*)s, *(const float4*)(s + 4));
                }
            } else {
                const u16* s = (k < 128)  ? &hbuf[(long)si[mt] * 128 + k]
                             : (k < 256)  ? &hbuf[(long)ti[mt] * 128 + (k - 128)]
                                          : &ebuf[grow[mt] * 128 + (k - 256)];
                a[mt] = *(const bf16x8*)s;
            }
        }
    };
    auto loadB = [&](int ch, bf16x8 (&b)[4]) {
        #pragma unroll
        for (int nt = 0; nt < 4; ++nt)
            b[nt] = *(const bf16x8*)&W1f[(size_t)(((ch * 2 + wn) * 4 + nt) * 512) + lane * 8];
    };

    // ---------------- layer 1: register-pipelined K-loop ----------------
    f32x4 acc[4][4];
    #pragma unroll
    for (int nt = 0; nt < 4; ++nt) {
        float bv = b1[wn * 64 + nt * 16 + lr];
        #pragma unroll
        for (int mt = 0; mt < 4; ++mt) acc[mt][nt] = (f32x4){bv, bv, bv, bv};
    }

    bf16x8 aP[2][4], bP[2][4];
    loadA(0, aP[0]); loadB(0, bP[0]);
    #pragma unroll
    for (int ch = 0; ch < NCH; ++ch) {
        const int cur = ch & 1, nxt = cur ^ 1;
        if (ch + 1 < NCH) { loadA(ch + 1, aP[nxt]); loadB(ch + 1, bP[nxt]); }
        #pragma unroll
        for (int mt = 0; mt < 4; ++mt)
            #pragma unroll
            for (int nt = 0; nt < 4; ++nt)
                acc[mt][nt] = __builtin_amdgcn_mfma_f32_16x16x32_bf16(
                                  aP[cur][mt], bP[cur][nt], acc[mt][nt], 0, 0, 0);
    }

    // relu -> Hs (C layout: col=lane&15, row=(lane>>4)*4+reg)
    #pragma unroll
    for (int mt = 0; mt < 4; ++mt)
        #pragma unroll
        for (int nt = 0; nt < 4; ++nt)
            #pragma unroll
            for (int reg = 0; reg < 4; ++reg) {
                int row = wm * 64 + mt * 16 + lq * 4 + reg;
                int col = wn * 64 + nt * 16 + lr;
                Hs[row * 136 + col] = f2bf(fmaxf(acc[mt][nt][reg], 0.f));
            }
    __syncthreads();

    // ---------------- layer 2 ----------------
    if (MODE == 4) {               // 128 -> 1 head
        float s = 0.f;
        int r = tid >> 1, k0 = (tid & 1) * 64;
        #pragma unroll
        for (int j = 0; j < 64; ++j)
            s += bf2f(Hs[r * 136 + k0 + j]) * w2s[k0 + j];
        part[tid] = s;
        __syncthreads();
        if (tid < 128) {
            long row = tile0 + tid;
            if (row < NROWS)
                ((float*)outp)[row] = part[tid * 2] + part[tid * 2 + 1] + bias2[0];
        }
        return;
    }

    f32x4 acc2[4][4];
    #pragma unroll
    for (int nt = 0; nt < 4; ++nt) {
        float bv = w2orb2[wn * 64 + nt * 16 + lr];
        #pragma unroll
        for (int mt = 0; mt < 4; ++mt) acc2[mt][nt] = (f32x4){bv, bv, bv, bv};
    }
    // pipelined layer 2: prefetch B frags, A from LDS
    bf16x8 b2P[2][4];
    #pragma unroll
    for (int nt = 0; nt < 4; ++nt)
        b2P[0][nt] = *(const bf16x8*)&W2f[(size_t)((0 * 2 + wn) * 4 + nt) * 512 + lane * 8];
    #pragma unroll
    for (int ch = 0; ch < 4; ++ch) {
        const int cur = ch & 1, nxt = cur ^ 1;
        if (ch + 1 < 4) {
            #pragma unroll
            for (int nt = 0; nt < 4; ++nt)
                b2P[nxt][nt] = *(const bf16x8*)
                    &W2f[(size_t)(((ch + 1) * 2 + wn) * 4 + nt) * 512 + lane * 8];
        }
        bf16x8 a[4];
        #pragma unroll
        for (int mt = 0; mt < 4; ++mt)
            a[mt] = *(const bf16x8*)&Hs[(wm * 64 + mt * 16 + lr) * 136 + ch * 32 + lq * 8];
        #pragma unroll
        for (int mt = 0; mt < 4; ++mt)
            #pragma unroll
            for (int nt = 0; nt < 4; ++nt)
                acc2[mt][nt] = __builtin_amdgcn_mfma_f32_16x16x32_bf16(
                                   a[mt], b2P[cur][nt], acc2[mt][nt], 0, 0, 0);
    }
    __syncthreads();               // all Hs reads done before overwrite
    #pragma unroll
    for (int mt = 0; mt < 4; ++mt)
        #pragma unroll
        for (int nt = 0; nt < 4; ++nt)
            #pragma unroll
            for (int reg = 0; reg < 4; ++reg) {
                int row = wm * 64 + mt * 16 + lq * 4 + reg;
                int col = wn * 64 + nt * 16 + lr;
                Hs[row * 136 + col] = f2bf(acc2[mt][nt][reg]);
            }
    __syncthreads();

    // residual + coalesced store
    u16* out = (u16*)outp;
    for (int f = tid; f < 1024; f += TPB) {
        int r = f >> 3, q = f & 7;
        long row = tile0 + r;
        if (row >= NROWS) continue;
        int col = q * 16;
        const u16* hp = &Hs[r * 136 + col];
        alignas(16) u16 ov[16];
        if (MODE == 2 || MODE == 3) {
            const u16* res = (MODE == 3) ? &ebuf[row * D + col] : &hbuf[row * D + col];
            #pragma unroll
            for (int j = 0; j < 16; ++j) ov[j] = f2bf(bf2f(hp[j]) + bf2f(res[j]));
        } else {
            #pragma unroll
            for (int j = 0; j < 16; ++j) ov[j] = hp[j];
        }
        *(uint4*)&out[row * D + col]     = *(const uint4*)&ov[0];
        *(uint4*)&out[row * D + col + 8] = *(const uint4*)&ov[8];
    }
}

// --------------------------- plain kernel symbols ---------------------------

__global__ void k_detect(const int* __restrict__ ei, int* __restrict__ flag) {
    if (threadIdx.x == 0 && blockIdx.x == 0) {
        int any = 0;
        for (int i = 0; i < 64; ++i) any |= ei[2 * i + 1];
        flag[0] = (any == 0) ? 1 : 0;
    }
}

// W [K][128] fp32 -> frag-major bf16: idx=((ch*2+wn)*4+nt)*512+lane*8+j
__global__ void k_prep2(const float* __restrict__ W, u16* __restrict__ dst,
                        int nch, int Kreal) {
    int total = nch * 4096;
    for (int i = blockIdx.x * TPB + threadIdx.x; i < total; i += gridDim.x * TPB) {
        int j    = i & 7;
        int lane = (i >> 3) & 63;
        int nt   = (i >> 9) & 3;
        int wnn  = (i >> 11) & 1;
        int ch   = i >> 12;
        int k = ch * 32 + (lane >> 4) * 8 + j;
        int n = wnn * 64 + nt * 16 + (lane & 15);
        dst[i] = f2bf((k < Kreal) ? W[(size_t)k * 128 + n] : 0.f);
    }
}

// ---- CSR build ----
__global__ void k_hist(const int* __restrict__ ei, const int* __restrict__ flag,
                       int* __restrict__ deg) {
    int i = blockIdx.x * TPB + threadIdx.x;
    if (i < NE) atomicAdd(&deg[load_idx(ei, (long)NE + i, flag[0])], 1);
}
__global__ void k_scanA(const int* __restrict__ deg, int* __restrict__ rp,
                        int* __restrict__ bsum) {
    __shared__ int s[256];
    int t = threadIdx.x, gi = blockIdx.x * 256 + t;
    s[t] = (gi < NN) ? deg[gi] : 0;
    for (int off = 1; off < 256; off <<= 1) {
        __syncthreads();
        int v = (t >= off) ? s[t - off] : 0;
        __syncthreads();
        s[t] += v;
    }
    __syncthreads();
    if (gi < NN) rp[gi] = s[t];
    if (t == 255) bsum[blockIdx.x] = s[255];
}
__global__ void k_scanB(int* __restrict__ bsum, int* __restrict__ boff, int nb) {
    if (threadIdx.x == 0 && blockIdx.x == 0) {
        int run = 0;
        for (int b = 0; b < nb; ++b) { boff[b] = run; run += bsum[b]; }
    }
}
__global__ void k_scanC(const int* __restrict__ deg, int* __restrict__ rp,
                        const int* __restrict__ boff) {
    int t = threadIdx.x, gi = blockIdx.x * 256 + t;
    if (gi >= NN) return;
    int incl = rp[gi] + boff[blockIdx.x];
    rp[gi] = incl - deg[gi];
    if (gi == NN - 1) rp[NN] = incl;
}
__global__ void k_fill(const int* __restrict__ ei, const int* __restrict__ flag,
                       int* __restrict__ cursor, int* __restrict__ eids) {
    int i = blockIdx.x * TPB + threadIdx.x;
    if (i >= NE) return;
    int n = load_idx(ei, (long)NE + i, flag[0]);
    int pos = atomicAdd(&cursor[n], 1);
    eids[pos] = i;
}

// msg[n] = sum over incoming edges of e[edge]  (one wave per node)
__global__ void k_gather(const u16* __restrict__ e, const int* __restrict__ rp,
                         const int* __restrict__ eids, float* __restrict__ msg) {
    int node = blockIdx.x * 4 + (threadIdx.x >> 6);
    if (node >= NN) return;
    int lane = threadIdx.x & 63;
    int beg = rp[node], end = rp[node + 1];
    float a0 = 0.f, a1 = 0.f;
    for (int i = beg; i < end; ++i) {
        unsigned v = ((const unsigned*)e)[(size_t)eids[i] * 64 + lane];
        a0 += bf2f((u16)(v & 0xffff));
        a1 += bf2f((u16)(v >> 16));
    }
    float2 o; o.x = a0; o.y = a1;
    *(float2*)&msg[(size_t)node * 128 + lane * 2] = o;
}

// ---- MLP kernel wrappers ----
__launch_bounds__(TPB)
__global__ void k_node_enc2(const float* nodes, const u16* W1f, const float* b1,
                            const u16* W2f, const float* b2, u16* h) {
    mfma2<32, 0>(nullptr, nullptr, nodes, nullptr, nullptr, W1f, b1, W2f, b2, nullptr, h);
}
__launch_bounds__(TPB)
__global__ void k_edge_enc2(const u16* h, const int* ei, const int* flag,
                            const u16* W1f, const float* b1,
                            const u16* W2f, const float* b2, u16* e) {
    mfma2<256, 1>(h, nullptr, nullptr, ei, flag, W1f, b1, W2f, b2, nullptr, e);
}
__launch_bounds__(TPB)
__global__ void k_node_upd2(const u16* h, const float* msg,
                            const u16* W1f, const float* b1,
                            const u16* W2f, const float* b2, u16* hout) {
    mfma2<256, 2>(h, nullptr, msg, nullptr, nullptr, W1f, b1, W2f, b2, nullptr, hout);
}
__launch_bounds__(TPB)
__global__ void k_edge_upd2(const u16* h, const u16* e, const int* ei, const int* flag,
                            const u16* W1f, const float* b1,
                            const u16* W2f, const float* b2, u16* eout) {
    mfma2<384, 3>(h, e, nullptr, ei, flag, W1f, b1, W2f, b2, nullptr, eout);
}
__launch_bounds__(TPB)
__global__ void k_decode2(const u16* h, const u16* e, const int* ei, const int* flag,
                          const u16* W1f, const float* b1,
                          const float* w2, const float* b2, float* pred) {
    mfma2<384, 4>(h, e, nullptr, ei, flag, W1f, b1, nullptr, w2, b2, pred);
}

// ---------------------------------------------------------------------------

extern "C" void kernel_launch(void* const* d_in, const int* in_sizes, int n_in,
                              void* d_out, int out_size, void* d_ws, size_t ws_size,
                              hipStream_t stream)
{
    const float* nodes = (const float*)d_in[0];
    const int*   ei    = (const int*)d_in[1];
    const float* ne_W1 = (const float*)d_in[2];  const float* ne_b1 = (const float*)d_in[3];
    const float* ne_W2 = (const float*)d_in[4];  const float* ne_b2 = (const float*)d_in[5];
    const float* ee_W1 = (const float*)d_in[6];  const float* ee_b1 = (const float*)d_in[7];
    const float* ee_W2 = (const float*)d_in[8];  const float* ee_b2 = (const float*)d_in[9];
    const float* nn_W1 = (const float*)d_in[10]; const float* nn_b1 = (const float*)d_in[11];
    const float* nn_W2 = (const float*)d_in[12]; const float* nn_b2 = (const float*)d_in[13];
    const float* en_W1 = (const float*)d_in[14]; const float* en_b1 = (const float*)d_in[15];
    const float* en_W2 = (const float*)d_in[16]; const float* en_b2 = (const float*)d_in[17];
    const float* pe_W1 = (const float*)d_in[18]; const float* pe_b1 = (const float*)d_in[19];
    const float* pe_W2 = (const float*)d_in[20]; const float* pe_b2 = (const float*)d_in[21];

    const size_t hN = (size_t)NN * D;
    const size_t eN = (size_t)NE * D;
    const int NB = (NN + 255) / 256;

    const size_t sNE1 = 32 * 128,  sNE2 = 128 * 128;
    const size_t sEE1 = 256 * 128, sEE2 = 128 * 128;
    const size_t sNN1 = 256 * 128, sNN2 = 128 * 128;
    const size_t sEN1 = 384 * 128, sEN2 = 128 * 128;
    const size_t sPE1 = 384 * 128;
    const size_t wTot = sNE1 + sNE2 + sEE1 + sEE2 + sNN1 + sNN2 + sEN1 + sEN2 + sPE1;

    const size_t need = 256 + hN * 2 + eN * 2 + hN * 4 + wTot * 2
                      + (size_t)NN * 4 + (size_t)(NN + 1) * 4 + (size_t)NN * 4
                      + (size_t)NE * 4 + 1024 * 4;
    if (ws_size < need) {
        hipMemsetAsync(d_out, 0x43, (size_t)out_size * sizeof(float), stream);
        return;
    }

    char* p = (char*)d_ws;
    int*   flag  = (int*)p;                   p += 256;
    u16*   h     = (u16*)p;                   p += hN * 2;
    u16*   e     = (u16*)p;                   p += eN * 2;
    float* msg   = (float*)p;                 p += hN * 4;
    float* stage = msg;                       // overlaps msg (dead at decode)
    u16*   ne1f  = (u16*)p;                   p += sNE1 * 2;
    u16*   ne2f  = (u16*)p;                   p += sNE2 * 2;
    u16*   ee1f  = (u16*)p;                   p += sEE1 * 2;
    u16*   ee2f  = (u16*)p;                   p += sEE2 * 2;
    u16*   nn1f  = (u16*)p;                   p += sNN1 * 2;
    u16*   nn2f  = (u16*)p;                   p += sNN2 * 2;
    u16*   en1f  = (u16*)p;                   p += sEN1 * 2;
    u16*   en2f  = (u16*)p;                   p += sEN2 * 2;
    u16*   pe1f  = (u16*)p;                   p += sPE1 * 2;
    int*   deg   = (int*)p;                   p += (size_t)NN * 4;
    int*   rp    = (int*)p;                   p += (size_t)(NN + 1) * 4;
    int*   cur   = (int*)p;                   p += (size_t)NN * 4;
    int*   eids  = (int*)p;                   p += (size_t)NE * 4;
    int*   bsum  = (int*)p;                   p += 512 * 4;
    int*   boff  = (int*)p;

    dim3 blk(TPB);
    k_detect<<<1, 64, 0, stream>>>(ei, flag);

    k_prep2<<<32, blk, 0, stream>>>(ne_W1, ne1f, 1, 16);
    k_prep2<<<32, blk, 0, stream>>>(ne_W2, ne2f, 4, 128);
    k_prep2<<<32, blk, 0, stream>>>(ee_W1, ee1f, 8, 256);
    k_prep2<<<32, blk, 0, stream>>>(ee_W2, ee2f, 4, 128);
    k_prep2<<<32, blk, 0, stream>>>(nn_W1, nn1f, 8, 256);
    k_prep2<<<32, blk, 0, stream>>>(nn_W2, nn2f, 4, 128);
    k_prep2<<<32, blk, 0, stream>>>(en_W1, en1f, 12, 384);
    k_prep2<<<32, blk, 0, stream>>>(en_W2, en2f, 4, 128);
    k_prep2<<<32, blk, 0, stream>>>(pe_W1, pe1f, 12, 384);

    // CSR build
    hipMemsetAsync(deg, 0, (size_t)NN * 4, stream);
    k_hist<<<(NE + TPB - 1) / TPB, blk, 0, stream>>>(ei, flag, deg);
    k_scanA<<<NB, blk, 0, stream>>>(deg, rp, bsum);
    k_scanB<<<1, 64, 0, stream>>>(bsum, boff, NB);
    k_scanC<<<NB, blk, 0, stream>>>(deg, rp, boff);
    hipMemcpyAsync(cur, rp, (size_t)NN * 4, hipMemcpyDeviceToDevice, stream);
    k_fill<<<(NE + TPB - 1) / TPB, blk, 0, stream>>>(ei, flag, cur, eids);

    const int EG = (NE + 127) / 128;    // 4688
    const int NG = (NN + 127) / 128;    // 782

    k_node_enc2<<<NG, blk, 0, stream>>>(nodes, ne1f, ne_b1, ne2f, ne_b2, h);
    k_edge_enc2<<<EG, blk, 0, stream>>>(h, ei, flag, ee1f, ee_b1, ee2f, ee_b2, e);

    for (int it = 0; it < 4; ++it) {
        k_gather<<<(NN + 3) / 4, blk, 0, stream>>>(e, rp, eids, msg);
        // e <- MLP_en([h_old[s], h_old[t], e_old]) + e_old   (uses pre-update h)
        k_edge_upd2<<<EG, blk, 0, stream>>>(h, e, ei, flag, en1f, en_b1, en2f, en_b2, e);
        // h <- MLP_nn([h_old, msg]) + h_old
        k_node_upd2<<<NG, blk, 0, stream>>>(h, msg, nn1f, nn_b1, nn2f, nn_b2, h);
    }

    k_decode2<<<EG, blk, 0, stream>>>(h, e, ei, flag, pe1f, pe_b1, pe_W2, pe_b2, stage);
    hipMemcpyAsync(d_out, stage, (size_t)NE * sizeof(float),
                   hipMemcpyDeviceToDevice, stream);
}

// Round 16
// 1497.819 us; speedup vs baseline: 1.1257x; 1.1257x over previous
//
#include <hip/hip_runtime.h>

// InteractionGNN on MI355X — Round 16: dual-path (factored if ws allows).
// ws_size ∈ [234.5, 285.7) MB (R14 pass / R15 ws-signal). Factored path now
// fits 262.5 MB: h ping-pong + ONE 51.2MB region time-shared by msg(fp32) and
// P(bf16) — order: gather(msg) -> node_upd(hOld,msg->hNew) -> pcomp(hOld->P)
// -> edge_upd(P,e). Fallback = proven R14 pipeline. Branch on ws_size only
// (constant per session -> graph-replay-safe). dur_us reveals which path ran.

#define TPB 256
constexpr int D    = 128;
constexpr int NN   = 100000;
constexpr int NE   = 600000;

typedef unsigned short u16;
typedef __attribute__((ext_vector_type(8))) short bf16x8;
typedef __attribute__((ext_vector_type(4))) float f32x4;

__device__ inline float bf2f(u16 x) { return __uint_as_float((unsigned)x << 16); }
__device__ inline u16 f2bf(float f) {   // round-to-nearest-even
    unsigned u = __float_as_uint(f);
    unsigned r = u + 0x7FFFu + ((u >> 16) & 1u);
    return (u16)(r >> 16);
}
__device__ inline int load_idx(const int* ei, long pos, int is64) {
    int v = is64 ? ei[2 * pos] : ei[pos];
    return (v < 0) ? 0 : (v >= NN ? NN - 1 : v);
}
__device__ inline bf16x8 pack8(float4 f0, float4 f1) {
    union { bf16x8 v; u16 t[8]; } u;
    u.t[0] = f2bf(f0.x); u.t[1] = f2bf(f0.y); u.t[2] = f2bf(f0.z); u.t[3] = f2bf(f0.w);
    u.t[4] = f2bf(f1.x); u.t[5] = f2bf(f1.y); u.t[6] = f2bf(f1.z); u.t[7] = f2bf(f1.w);
    return u.v;
}
__device__ inline bf16x8 zero8() {
    union { bf16x8 v; u16 t[8]; } u;
    #pragma unroll
    for (int j = 0; j < 8; ++j) u.t[j] = 0;
    return u.v;
}

// ---------------------------------------------------------------------------
// Unified MFMA MLP body. Block 128 rows x 128 cols; 4 waves 2x2; wave 64x64.
// MODE 0: node-enc (K=32 pad, fin fp32[*,16])
// MODE 1: edge-enc gathered (K=256 [h_s,h_t])            [fallback]
// MODE 2: node-upd (K=256 [h, msg fp32], +h resid)
// MODE 3: edge-upd gathered (K=384 [h_s,h_t,e], +e)      [fallback]
// MODE 4: decode gathered (K=384, head)                  [fallback]
// MODE 5: pcomp (K=128 from h; raw; out stride 256)      [factored]
// MODE 6: edge-enc P-based (fixup only)                  [factored]
// MODE 7: edge-upd (K=128 e-stream + P fixup, +e resid)  [factored]
// MODE 8: decode (K=128 e-stream + P fixup, head)        [factored]
// W1f/W2f frag-major bf16: idx = ((ch*2+wn)*4+nt)*512 + lane*8.
// Pbuf: row*256 + [0:128)=P_s, [128:256)=P_t.
// ---------------------------------------------------------------------------
template<int MODE>
__device__ inline void mlp_v3(const u16* hbuf, const u16* ebuf, const float* fin,
                              const u16* __restrict__ Pbuf,
                              const int* ei, const int* idxFlag,
                              const u16* __restrict__ W1f, const float* b1,
                              const u16* __restrict__ W2f, const float* w2orb2,
                              const float* bias2, void* outp)
{
    constexpr int NCH = (MODE == 0) ? 1 : (MODE == 1) ? 8 : (MODE == 2) ? 8
                      : (MODE == 3) ? 12 : (MODE == 4) ? 12 : (MODE == 5) ? 4
                      : (MODE == 6) ? 0 : 4;
    constexpr bool NODE = (MODE == 0 || MODE == 2 || MODE == 5);
    constexpr long NROWS = NODE ? NN : NE;
    constexpr bool GATH = (MODE == 1 || MODE == 3 || MODE == 4);
    constexpr bool FIX  = (MODE >= 6);
    constexpr bool HEAD = (MODE == 4 || MODE == 8);

    __shared__ alignas(16) u16 Hs[128 * 136];   // 34.8 KB
    __shared__ int   sIdx[128];
    __shared__ int   tIdx[128];
    __shared__ float part[256];
    __shared__ float w2s[128];
    __shared__ float b1s[128];

    const int tid  = threadIdx.x;
    const int lane = tid & 63;
    const int wave = tid >> 6;
    const int wm   = wave >> 1;
    const int wn   = wave & 1;
    const int lr   = lane & 15;
    const int lq   = lane >> 4;
    const long tile0 = (long)blockIdx.x * 128;

    if (GATH || FIX) {
        const int is64 = idxFlag[0];
        if (tid < 128) {
            long p = tile0 + tid; if (p > NE - 1) p = NE - 1;
            sIdx[tid] = load_idx(ei, p, is64);
        } else {
            int r = tid - 128;
            long p = tile0 + r; if (p > NE - 1) p = NE - 1;
            tIdx[r] = load_idx(ei, (long)NE + p, is64);
        }
        if (HEAD && tid < 128) w2s[tid] = w2orb2[tid];
        if (MODE == 6 && tid < 128) b1s[tid] = b1[tid];
        __syncthreads();
    }

    long grow[4]; int si[4], ti[4];
    #pragma unroll
    for (int mt = 0; mt < 4; ++mt) {
        int rloc = wm * 64 + mt * 16 + lr;
        long g = tile0 + rloc; if (g > NROWS - 1) g = NROWS - 1;
        grow[mt] = g;
        if (GATH) { si[mt] = sIdx[rloc]; ti[mt] = tIdx[rloc]; }
    }

    // ---------------- layer 1 MFMA ----------------
    if constexpr (MODE != 6) {
        f32x4 acc[4][4];
        #pragma unroll
        for (int nt = 0; nt < 4; ++nt) {
            float bv = (MODE == 5) ? 0.f : b1[wn * 64 + nt * 16 + lr];
            #pragma unroll
            for (int mt = 0; mt < 4; ++mt) acc[mt][nt] = (f32x4){bv, bv, bv, bv};
        }
        #pragma unroll
        for (int ch = 0; ch < NCH; ++ch) {
            const int k = ch * 32 + lq * 8;
            bf16x8 a[4], b[4];
            #pragma unroll
            for (int mt = 0; mt < 4; ++mt) {
                if (MODE == 0) {
                    if (lq < 2) {
                        const float* s = &fin[grow[mt] * 16 + lq * 8];
                        a[mt] = pack8(*(const float4*)s, *(const float4*)(s + 4));
                    } else a[mt] = zero8();
                } else if (MODE == 1) {
                    const u16* s = (k < 128) ? &hbuf[(long)si[mt] * 128 + k]
                                             : &hbuf[(long)ti[mt] * 128 + (k - 128)];
                    a[mt] = *(const bf16x8*)s;
                } else if (MODE == 2) {
                    if (k < 128) {
                        a[mt] = *(const bf16x8*)&hbuf[grow[mt] * 128 + k];
                    } else {
                        const float* s = &fin[grow[mt] * 128 + (k - 128)];
                        a[mt] = pack8(*(const float4*)s, *(const float4*)(s + 4));
                    }
                } else if (MODE == 3 || MODE == 4) {
                    const u16* s = (k < 128)  ? &hbuf[(long)si[mt] * 128 + k]
                                 : (k < 256)  ? &hbuf[(long)ti[mt] * 128 + (k - 128)]
                                              : &ebuf[grow[mt] * 128 + (k - 256)];
                    a[mt] = *(const bf16x8*)s;
                } else if (MODE == 5) {
                    a[mt] = *(const bf16x8*)&hbuf[grow[mt] * 128 + k];
                } else {  // 7,8
                    a[mt] = *(const bf16x8*)&ebuf[grow[mt] * 128 + k];
                }
            }
            #pragma unroll
            for (int nt = 0; nt < 4; ++nt)
                b[nt] = *(const bf16x8*)&W1f[(size_t)(((ch * 2 + wn) * 4 + nt) * 512) + lane * 8];
            #pragma unroll
            for (int mt = 0; mt < 4; ++mt)
                #pragma unroll
                for (int nt = 0; nt < 4; ++nt)
                    acc[mt][nt] = __builtin_amdgcn_mfma_f32_16x16x32_bf16(
                                      a[mt], b[nt], acc[mt][nt], 0, 0, 0);
        }
        #pragma unroll
        for (int mt = 0; mt < 4; ++mt)
            #pragma unroll
            for (int nt = 0; nt < 4; ++nt)
                #pragma unroll
                for (int reg = 0; reg < 4; ++reg) {
                    int row = wm * 64 + mt * 16 + lq * 4 + reg;
                    int col = wn * 64 + nt * 16 + lr;
                    float v = acc[mt][nt][reg];
                    if (MODE <= 4) v = fmaxf(v, 0.f);   // relu now; 5/7/8 raw
                    Hs[row * 136 + col] = f2bf(v);
                }
        __syncthreads();
    }

    // ---------------- P fix-up: Hs = relu(base + P_s + P_t) ----------------
    if constexpr (FIX) {
        for (int f = tid; f < 1024; f += TPB) {
            int r = f >> 3, q = f & 7, col = q * 16;
            int s = sIdx[r], t = tIdx[r];
            const u16* ps = &Pbuf[(size_t)s * 256 + col];
            const u16* pt = &Pbuf[(size_t)t * 256 + 128 + col];
            alignas(16) u16 psv[16], ptv[16];
            *(uint4*)&psv[0] = *(const uint4*)&ps[0];
            *(uint4*)&psv[8] = *(const uint4*)&ps[8];
            *(uint4*)&ptv[0] = *(const uint4*)&pt[0];
            *(uint4*)&ptv[8] = *(const uint4*)&pt[8];
            #pragma unroll
            for (int j = 0; j < 16; ++j) {
                float base = (MODE == 6) ? b1s[col + j] : bf2f(Hs[r * 136 + col + j]);
                float v = base + bf2f(psv[j]) + bf2f(ptv[j]);
                Hs[r * 136 + col + j] = f2bf(fmaxf(v, 0.f));
            }
        }
        __syncthreads();
    }

    // ---------------- outputs ----------------
    if constexpr (MODE == 5) {      // raw hidden -> P slice (row stride 256)
        u16* out = (u16*)outp;
        for (int f = tid; f < 1024; f += TPB) {
            int r = f >> 3, q = f & 7, col = q * 16;
            long row = tile0 + r;
            if (row >= NROWS) continue;
            *(uint4*)&out[row * 256 + col]     = *(const uint4*)&Hs[r * 136 + col];
            *(uint4*)&out[row * 256 + col + 8] = *(const uint4*)&Hs[r * 136 + col + 8];
        }
        return;
    }

    if constexpr (HEAD) {           // 128 -> 1
        float s = 0.f;
        int r = tid >> 1, k0 = (tid & 1) * 64;
        #pragma unroll
        for (int j = 0; j < 64; ++j)
            s += bf2f(Hs[r * 136 + k0 + j]) * w2s[k0 + j];
        part[tid] = s;
        __syncthreads();
        if (tid < 128) {
            long row = tile0 + tid;
            if (row < NROWS)
                ((float*)outp)[row] = part[tid * 2] + part[tid * 2 + 1] + bias2[0];
        }
        return;
    }

    if constexpr (MODE == 0 || MODE == 1 || MODE == 2 || MODE == 3 ||
                  MODE == 6 || MODE == 7) {
        f32x4 acc2[4][4];
        #pragma unroll
        for (int nt = 0; nt < 4; ++nt) {
            float bv = w2orb2[wn * 64 + nt * 16 + lr];
            #pragma unroll
            for (int mt = 0; mt < 4; ++mt) acc2[mt][nt] = (f32x4){bv, bv, bv, bv};
        }
        #pragma unroll
        for (int ch = 0; ch < 4; ++ch) {
            bf16x8 a[4], b[4];
            #pragma unroll
            for (int mt = 0; mt < 4; ++mt)
                a[mt] = *(const bf16x8*)&Hs[(wm * 64 + mt * 16 + lr) * 136 + ch * 32 + lq * 8];
            #pragma unroll
            for (int nt = 0; nt < 4; ++nt)
                b[nt] = *(const bf16x8*)&W2f[(size_t)(((ch * 2 + wn) * 4 + nt) * 512) + lane * 8];
            #pragma unroll
            for (int mt = 0; mt < 4; ++mt)
                #pragma unroll
                for (int nt = 0; nt < 4; ++nt)
                    acc2[mt][nt] = __builtin_amdgcn_mfma_f32_16x16x32_bf16(
                                       a[mt], b[nt], acc2[mt][nt], 0, 0, 0);
        }
        __syncthreads();
        #pragma unroll
        for (int mt = 0; mt < 4; ++mt)
            #pragma unroll
            for (int nt = 0; nt < 4; ++nt)
                #pragma unroll
                for (int reg = 0; reg < 4; ++reg) {
                    int row = wm * 64 + mt * 16 + lq * 4 + reg;
                    int col = wn * 64 + nt * 16 + lr;
                    Hs[row * 136 + col] = f2bf(acc2[mt][nt][reg]);
                }
        __syncthreads();

        u16* out = (u16*)outp;
        for (int f = tid; f < 1024; f += TPB) {
            int r = f >> 3, q = f & 7, col = q * 16;
            long row = tile0 + r;
            if (row >= NROWS) continue;
            const u16* hp = &Hs[r * 136 + col];
            alignas(16) u16 ov[16];
            if (MODE == 2 || MODE == 3 || MODE == 7) {
                const u16* res = (MODE == 2) ? &hbuf[row * 128 + col] : &ebuf[row * 128 + col];
                #pragma unroll
                for (int j = 0; j < 16; ++j) ov[j] = f2bf(bf2f(hp[j]) + bf2f(res[j]));
            } else {
                #pragma unroll
                for (int j = 0; j < 16; ++j) ov[j] = hp[j];
            }
            *(uint4*)&out[row * 128 + col]     = *(const uint4*)&ov[0];
            *(uint4*)&out[row * 128 + col + 8] = *(const uint4*)&ov[8];
        }
    }
}

// --------------------------- plain kernel symbols ---------------------------

__global__ void k_detect(const int* __restrict__ ei, int* __restrict__ flag) {
    if (threadIdx.x == 0 && blockIdx.x == 0) {
        int any = 0;
        for (int i = 0; i < 64; ++i) any |= ei[2 * i + 1];
        flag[0] = (any == 0) ? 1 : 0;
    }
}

__global__ void k_prep2(const float* __restrict__ W, u16* __restrict__ dst,
                        int nch, int Kreal) {
    int total = nch * 4096;
    for (int i = blockIdx.x * TPB + threadIdx.x; i < total; i += gridDim.x * TPB) {
        int j    = i & 7;
        int lane = (i >> 3) & 63;
        int nt   = (i >> 9) & 3;
        int wnn  = (i >> 11) & 1;
        int ch   = i >> 12;
        int k = ch * 32 + (lane >> 4) * 8 + j;
        int n = wnn * 64 + nt * 16 + (lane & 15);
        dst[i] = f2bf((k < Kreal) ? W[(size_t)k * 128 + n] : 0.f);
    }
}

// ---- CSR build ----
__global__ void k_hist(const int* __restrict__ ei, const int* __restrict__ flag,
                       int* __restrict__ deg) {
    int i = blockIdx.x * TPB + threadIdx.x;
    if (i < NE) atomicAdd(&deg[load_idx(ei, (long)NE + i, flag[0])], 1);
}
__global__ void k_scanA(const int* __restrict__ deg, int* __restrict__ rp,
                        int* __restrict__ bsum) {
    __shared__ int s[256];
    int t = threadIdx.x, gi = blockIdx.x * 256 + t;
    s[t] = (gi < NN) ? deg[gi] : 0;
    for (int off = 1; off < 256; off <<= 1) {
        __syncthreads();
        int v = (t >= off) ? s[t - off] : 0;
        __syncthreads();
        s[t] += v;
    }
    __syncthreads();
    if (gi < NN) rp[gi] = s[t];
    if (t == 255) bsum[blockIdx.x] = s[255];
}
__global__ void k_scanB(int* __restrict__ bsum, int* __restrict__ boff, int nb) {
    if (threadIdx.x == 0 && blockIdx.x == 0) {
        int run = 0;
        for (int b = 0; b < nb; ++b) { boff[b] = run; run += bsum[b]; }
    }
}
__global__ void k_scanC(const int* __restrict__ deg, int* __restrict__ rp,
                        const int* __restrict__ boff) {
    int t = threadIdx.x, gi = blockIdx.x * 256 + t;
    if (gi >= NN) return;
    int incl = rp[gi] + boff[blockIdx.x];
    rp[gi] = incl - deg[gi];
    if (gi == NN - 1) rp[NN] = incl;
}
__global__ void k_fill(const int* __restrict__ ei, const int* __restrict__ flag,
                       int* __restrict__ cursor, int* __restrict__ eids) {
    int i = blockIdx.x * TPB + threadIdx.x;
    if (i >= NE) return;
    int n = load_idx(ei, (long)NE + i, flag[0]);
    int pos = atomicAdd(&cursor[n], 1);
    eids[pos] = i;
}

__global__ void k_gather(const u16* __restrict__ e, const int* __restrict__ rp,
                         const int* __restrict__ eids, float* __restrict__ msg) {
    int node = blockIdx.x * 4 + (threadIdx.x >> 6);
    if (node >= NN) return;
    int lane = threadIdx.x & 63;
    int beg = rp[node], end = rp[node + 1];
    float a0 = 0.f, a1 = 0.f;
    for (int i = beg; i < end; ++i) {
        unsigned v = ((const unsigned*)e)[(size_t)eids[i] * 64 + lane];
        a0 += bf2f((u16)(v & 0xffff));
        a1 += bf2f((u16)(v >> 16));
    }
    float2 o; o.x = a0; o.y = a1;
    *(float2*)&msg[(size_t)node * 128 + lane * 2] = o;
}

// ---- wrappers ----
__launch_bounds__(TPB)
__global__ void k_node_enc(const float* nodes, const u16* W1f, const float* b1,
                           const u16* W2f, const float* b2, u16* h) {
    mlp_v3<0>(nullptr, nullptr, nodes, nullptr, nullptr, nullptr, W1f, b1, W2f, b2, nullptr, h);
}
__launch_bounds__(TPB)
__global__ void k_node_upd(const u16* h, const float* msg,
                           const u16* W1f, const float* b1,
                           const u16* W2f, const float* b2, u16* hout) {
    mlp_v3<2>(h, nullptr, msg, nullptr, nullptr, nullptr, W1f, b1, W2f, b2, nullptr, hout);
}
// fallback (gathered)
__launch_bounds__(TPB)
__global__ void k_edge_encF(const u16* h, const int* ei, const int* flag,
                            const u16* W1f, const float* b1,
                            const u16* W2f, const float* b2, u16* e) {
    mlp_v3<1>(h, nullptr, nullptr, nullptr, ei, flag, W1f, b1, W2f, b2, nullptr, e);
}
__launch_bounds__(TPB)
__global__ void k_edge_updF(const u16* h, const u16* e, const int* ei, const int* flag,
                            const u16* W1f, const float* b1,
                            const u16* W2f, const float* b2, u16* eout) {
    mlp_v3<3>(h, e, nullptr, nullptr, ei, flag, W1f, b1, W2f, b2, nullptr, eout);
}
__launch_bounds__(TPB)
__global__ void k_decodeF(const u16* h, const u16* e, const int* ei, const int* flag,
                          const u16* W1f, const float* b1,
                          const float* w2, const float* b2, float* pred) {
    mlp_v3<4>(h, e, nullptr, nullptr, ei, flag, W1f, b1, nullptr, w2, b2, pred);
}
// factored
__launch_bounds__(TPB)
__global__ void k_pcomp(const u16* h, const u16* W1fbase, u16* Pout) {
    const u16* W1f = W1fbase + (size_t)blockIdx.y * (4 * 4096);
    u16* out = Pout + (size_t)blockIdx.y * 128;
    mlp_v3<5>(h, nullptr, nullptr, nullptr, nullptr, nullptr,
              W1f, nullptr, nullptr, nullptr, nullptr, out);
}
__launch_bounds__(TPB)
__global__ void k_edge_encP(const u16* P, const int* ei, const int* flag,
                            const float* b1, const u16* W2f, const float* b2, u16* e) {
    mlp_v3<6>(nullptr, nullptr, nullptr, P, ei, flag, nullptr, b1, W2f, b2, nullptr, e);
}
__launch_bounds__(TPB)
__global__ void k_edge_updP(const u16* e, const u16* P, const int* ei, const int* flag,
                            const u16* W1fe, const float* b1,
                            const u16* W2f, const float* b2, u16* eout) {
    mlp_v3<7>(nullptr, e, nullptr, P, ei, flag, W1fe, b1, W2f, b2, nullptr, eout);
}
__launch_bounds__(TPB)
__global__ void k_decodeP(const u16* e, const u16* P, const int* ei, const int* flag,
                          const u16* W1fe, const float* b1,
                          const float* w2, const float* b2, float* pred) {
    mlp_v3<8>(nullptr, e, nullptr, P, ei, flag, W1fe, b1, nullptr, w2, b2, pred);
}

// ---------------------------------------------------------------------------

extern "C" void kernel_launch(void* const* d_in, const int* in_sizes, int n_in,
                              void* d_out, int out_size, void* d_ws, size_t ws_size,
                              hipStream_t stream)
{
    const float* nodes = (const float*)d_in[0];
    const int*   ei    = (const int*)d_in[1];
    const float* ne_W1 = (const float*)d_in[2];  const float* ne_b1 = (const float*)d_in[3];
    const float* ne_W2 = (const float*)d_in[4];  const float* ne_b2 = (const float*)d_in[5];
    const float* ee_W1 = (const float*)d_in[6];  const float* ee_b1 = (const float*)d_in[7];
    const float* ee_W2 = (const float*)d_in[8];  const float* ee_b2 = (const float*)d_in[9];
    const float* nn_W1 = (const float*)d_in[10]; const float* nn_b1 = (const float*)d_in[11];
    const float* nn_W2 = (const float*)d_in[12]; const float* nn_b2 = (const float*)d_in[13];
    const float* en_W1 = (const float*)d_in[14]; const float* en_b1 = (const float*)d_in[15];
    const float* en_W2 = (const float*)d_in[16]; const float* en_b2 = (const float*)d_in[17];
    const float* pe_W1 = (const float*)d_in[18]; const float* pe_b1 = (const float*)d_in[19];
    const float* pe_W2 = (const float*)d_in[20]; const float* pe_b2 = (const float*)d_in[21];

    const size_t hN = (size_t)NN * D;
    const size_t eN = (size_t)NE * D;
    const int NB = (NN + 255) / 256;

    const size_t wTot = (size_t)(32 + 128 + 256 + 128 + 256 + 128 + 384 + 128 + 384) * 128;
    const size_t csrB = (size_t)NN * 4 + (size_t)(NN + 1) * 4 + (size_t)NN * 4
                      + (size_t)NE * 4 + 1024 * 4;
    const size_t shB  = hN * 4;                     // shared msg(fp32) / P(bf16) region
    const size_t needFall = 256 + hN * 2 + eN * 2 + hN * 4 + wTot * 2 + csrB;
    const size_t needFact = 256 + hN * 2 * 2 + eN * 2 + shB + (size_t)NE * 4
                          + wTot * 2 + csrB;

    const bool factored = (ws_size >= needFact);
    if (!factored && ws_size < needFall) {
        hipMemsetAsync(d_out, 0x43, (size_t)out_size * sizeof(float), stream);
        return;
    }

    // ---- layout ----
    char* p = (char*)d_ws;
    int*   flag = (int*)p;                 p += 256;
    u16*   h0   = (u16*)p;                 p += hN * 2;
    u16*   h1   = nullptr;
    if (factored) { h1 = (u16*)p;          p += hN * 2; }
    u16*   e    = (u16*)p;                 p += eN * 2;
    char*  shared = p;                     p += shB;     // msg fp32 / P bf16
    float* stage;
    if (factored) { stage = (float*)p;     p += (size_t)NE * 4; }
    else          { stage = (float*)shared; }            // overlaps msg (dead at decode)
    u16* wbase = (u16*)p;
    u16* ne1f = wbase;            u16* ne2f = ne1f + (size_t)32  * 128;
    u16* ee1f = ne2f + (size_t)128 * 128; u16* ee2f = ee1f + (size_t)256 * 128;
    u16* nn1f = ee2f + (size_t)128 * 128; u16* nn2f = nn1f + (size_t)256 * 128;
    u16* en1f = nn2f + (size_t)128 * 128; u16* en2f = en1f + (size_t)384 * 128;
    u16* pe1f = en2f + (size_t)128 * 128;
    p = (char*)(pe1f + (size_t)384 * 128);
    int* deg  = (int*)p;                   p += (size_t)NN * 4;
    int* rp   = (int*)p;                   p += (size_t)(NN + 1) * 4;
    int* cur  = (int*)p;                   p += (size_t)NN * 4;
    int* eids = (int*)p;                   p += (size_t)NE * 4;
    int* bsum = (int*)p;                   p += 512 * 4;
    int* boff = (int*)p;

    float* msg = (float*)shared;
    u16*   P   = (u16*)shared;

    dim3 blk(TPB);
    k_detect<<<1, 64, 0, stream>>>(ei, flag);

    k_prep2<<<32, blk, 0, stream>>>(ne_W1, ne1f, 1, 16);
    k_prep2<<<32, blk, 0, stream>>>(ne_W2, ne2f, 4, 128);
    k_prep2<<<32, blk, 0, stream>>>(ee_W1, ee1f, 8, 256);
    k_prep2<<<32, blk, 0, stream>>>(ee_W2, ee2f, 4, 128);
    k_prep2<<<32, blk, 0, stream>>>(nn_W1, nn1f, 8, 256);
    k_prep2<<<32, blk, 0, stream>>>(nn_W2, nn2f, 4, 128);
    k_prep2<<<32, blk, 0, stream>>>(en_W1, en1f, 12, 384);
    k_prep2<<<32, blk, 0, stream>>>(en_W2, en2f, 4, 128);
    k_prep2<<<32, blk, 0, stream>>>(pe_W1, pe1f, 12, 384);

    hipMemsetAsync(deg, 0, (size_t)NN * 4, stream);
    k_hist<<<(NE + TPB - 1) / TPB, blk, 0, stream>>>(ei, flag, deg);
    k_scanA<<<NB, blk, 0, stream>>>(deg, rp, bsum);
    k_scanB<<<1, 64, 0, stream>>>(bsum, boff, NB);
    k_scanC<<<NB, blk, 0, stream>>>(deg, rp, boff);
    hipMemcpyAsync(cur, rp, (size_t)NN * 4, hipMemcpyDeviceToDevice, stream);
    k_fill<<<(NE + TPB - 1) / TPB, blk, 0, stream>>>(ei, flag, cur, eids);

    const int EG = (NE + 127) / 128;    // 4688
    const int NG = (NN + 127) / 128;    // 782
    dim3 pg(NG, 2);

    k_node_enc<<<NG, blk, 0, stream>>>(nodes, ne1f, ne_b1, ne2f, ne_b2, h0);

    if (factored) {
        k_pcomp<<<pg, blk, 0, stream>>>(h0, ee1f, P);
        k_edge_encP<<<EG, blk, 0, stream>>>(P, ei, flag, ee_b1, ee2f, ee_b2, e);

        u16* hOld = h0; u16* hNew = h1;
        for (int it = 0; it < 4; ++it) {
            k_gather<<<(NN + 3) / 4, blk, 0, stream>>>(e, rp, eids, msg);
            // h_new <- MLP_nn([h_old, msg]) + h_old   (msg dead after this)
            k_node_upd<<<NG, blk, 0, stream>>>(hOld, msg, nn1f, nn_b1, nn2f, nn_b2, hNew);
            // P <- h_old @ en_W1[s|t]   (overwrites msg region)
            k_pcomp<<<pg, blk, 0, stream>>>(hOld, en1f, P);
            // e <- MLP_en(P_s + P_t + e@W1_e + b1) + e
            k_edge_updP<<<EG, blk, 0, stream>>>(e, P, ei, flag,
                                                en1f + 8 * 4096, en_b1, en2f, en_b2, e);
            u16* t = hOld; hOld = hNew; hNew = t;
        }
        k_pcomp<<<pg, blk, 0, stream>>>(hOld, pe1f, P);
        k_decodeP<<<EG, blk, 0, stream>>>(e, P, ei, flag,
                                          pe1f + 8 * 4096, pe_b1, pe_W2, pe_b2, stage);
    } else {
        k_edge_encF<<<EG, blk, 0, stream>>>(h0, ei, flag, ee1f, ee_b1, ee2f, ee_b2, e);
        for (int it = 0; it < 4; ++it) {
            k_gather<<<(NN + 3) / 4, blk, 0, stream>>>(e, rp, eids, msg);
            k_edge_updF<<<EG, blk, 0, stream>>>(h0, e, ei, flag,
                                                en1f, en_b1, en2f, en_b2, e);
            k_node_upd<<<NG, blk, 0, stream>>>(h0, msg, nn1f, nn_b1, nn2f, nn_b2, h0);
        }
        k_decodeF<<<EG, blk, 0, stream>>>(h0, e, ei, flag,
                                          pe1f, pe_b1, pe_W2, pe_b2, stage);
    }

    hipMemcpyAsync(d_out, stage, (size_t)NE * sizeof(float),
                   hipMemcpyDeviceToDevice, stream);
}

// Round 17
// 1436.132 us; speedup vs baseline: 1.1741x; 1.0430x over previous
//
#include <hip/hip_runtime.h>

// InteractionGNN on MI355X — Round 17: e stored in CSR (dest-sorted) order.
// All edge kernels work in CSR position space; orig edge id (eids) used only
// for s/t lookup + decode output scatter. Wins: (1) msg gather is fully
// sequential (no indirection); (2) P_t fixup gathers are cache-local (CSR
// groups edges by destination). Factored pipeline of R16 otherwise unchanged:
// relu([h_s,h_t,e]@W1+b1) == relu(P_s[s]+P_t[t]+e@W1_e+b1), P per-node.
// ws = 262.5 MB (proven fit).

#define TPB 256
constexpr int D    = 128;
constexpr int NN   = 100000;
constexpr int NE   = 600000;

typedef unsigned short u16;
typedef __attribute__((ext_vector_type(8))) short bf16x8;
typedef __attribute__((ext_vector_type(4))) float f32x4;

__device__ inline float bf2f(u16 x) { return __uint_as_float((unsigned)x << 16); }
__device__ inline u16 f2bf(float f) {   // round-to-nearest-even
    unsigned u = __float_as_uint(f);
    unsigned r = u + 0x7FFFu + ((u >> 16) & 1u);
    return (u16)(r >> 16);
}
__device__ inline int load_idx(const int* ei, long pos, int is64) {
    int v = is64 ? ei[2 * pos] : ei[pos];
    return (v < 0) ? 0 : (v >= NN ? NN - 1 : v);
}
__device__ inline bf16x8 pack8(float4 f0, float4 f1) {
    union { bf16x8 v; u16 t[8]; } u;
    u.t[0] = f2bf(f0.x); u.t[1] = f2bf(f0.y); u.t[2] = f2bf(f0.z); u.t[3] = f2bf(f0.w);
    u.t[4] = f2bf(f1.x); u.t[5] = f2bf(f1.y); u.t[6] = f2bf(f1.z); u.t[7] = f2bf(f1.w);
    return u.v;
}
__device__ inline bf16x8 zero8() {
    union { bf16x8 v; u16 t[8]; } u;
    #pragma unroll
    for (int j = 0; j < 8; ++j) u.t[j] = 0;
    return u.v;
}

// ---------------------------------------------------------------------------
// MFMA MLP body. Block 128 rows x 128 cols; 4 waves 2x2; wave 64x64.
// MODE 0: node-enc (K=32 pad, fin fp32[*,16])
// MODE 2: node-upd (K=256 [h, msg fp32], +h resid)
// MODE 5: pcomp (K=128 from h; raw pre-activation; out bf16 stride 256)
// MODE 6: edge-enc (layer1 = relu(b1+P_s+P_t); layer2; out e at CSR pos)
// MODE 7: edge-upd (K=128 e-stream(CSR) + P fixup; +e resid; out e at CSR pos)
// MODE 8: decode (K=128 e-stream + P fixup; head; scatter out[eid] fp32)
// W1f/W2f frag-major bf16: idx = ((ch*2+wn)*4+nt)*512 + lane*8.
// Pbuf: node*256 + [0:128)=P_s, [128:256)=P_t.  eids: CSR pos -> orig edge.
// ---------------------------------------------------------------------------
template<int MODE>
__device__ inline void mlp_v3(const u16* hbuf, const u16* ebuf, const float* fin,
                              const u16* __restrict__ Pbuf,
                              const int* ei, const int* __restrict__ eids,
                              const int* idxFlag,
                              const u16* __restrict__ W1f, const float* b1,
                              const u16* __restrict__ W2f, const float* w2orb2,
                              const float* bias2, void* outp)
{
    constexpr int NCH = (MODE == 0) ? 1 : (MODE == 2) ? 8 : (MODE == 5) ? 4
                      : (MODE == 6) ? 0 : 4;
    constexpr bool NODE = (MODE == 0 || MODE == 2 || MODE == 5);
    constexpr long NROWS = NODE ? NN : NE;
    constexpr bool FIX  = (MODE >= 6);
    constexpr bool HEAD = (MODE == 8);

    __shared__ alignas(16) u16 Hs[128 * 136];   // 34.8 KB
    __shared__ int   sIdx[128];
    __shared__ int   tIdx[128];
    __shared__ int   eidS[128];
    __shared__ float part[256];
    __shared__ float w2s[128];
    __shared__ float b1s[128];

    const int tid  = threadIdx.x;
    const int lane = tid & 63;
    const int wave = tid >> 6;
    const int wm   = wave >> 1;
    const int wn   = wave & 1;
    const int lr   = lane & 15;
    const int lq   = lane >> 4;
    const long tile0 = (long)blockIdx.x * 128;

    if (FIX) {
        const int is64 = idxFlag[0];
        if (tid < 128) {
            long pos = tile0 + tid; if (pos > NE - 1) pos = NE - 1;
            int eid = eids[pos];
            eid = (eid < 0) ? 0 : (eid >= NE ? NE - 1 : eid);
            eidS[tid] = eid;
            sIdx[tid] = load_idx(ei, eid, is64);
            tIdx[tid] = load_idx(ei, (long)NE + eid, is64);
        }
        if (HEAD && tid < 128) w2s[tid] = w2orb2[tid];
        if (MODE == 6 && tid < 128) b1s[tid] = b1[tid];
        __syncthreads();
    }

    long grow[4];
    #pragma unroll
    for (int mt = 0; mt < 4; ++mt) {
        int rloc = wm * 64 + mt * 16 + lr;
        long g = tile0 + rloc; if (g > NROWS - 1) g = NROWS - 1;
        grow[mt] = g;
    }

    // ---------------- layer 1 MFMA (modes 0,2,5,7,8) ----------------
    if constexpr (MODE != 6) {
        f32x4 acc[4][4];
        #pragma unroll
        for (int nt = 0; nt < 4; ++nt) {
            float bv = (MODE == 5) ? 0.f : b1[wn * 64 + nt * 16 + lr];
            #pragma unroll
            for (int mt = 0; mt < 4; ++mt) acc[mt][nt] = (f32x4){bv, bv, bv, bv};
        }
        #pragma unroll
        for (int ch = 0; ch < NCH; ++ch) {
            const int k = ch * 32 + lq * 8;
            bf16x8 a[4], b[4];
            #pragma unroll
            for (int mt = 0; mt < 4; ++mt) {
                if (MODE == 0) {
                    if (lq < 2) {
                        const float* s = &fin[grow[mt] * 16 + lq * 8];
                        a[mt] = pack8(*(const float4*)s, *(const float4*)(s + 4));
                    } else a[mt] = zero8();
                } else if (MODE == 2) {
                    if (k < 128) {
                        a[mt] = *(const bf16x8*)&hbuf[grow[mt] * 128 + k];
                    } else {
                        const float* s = &fin[grow[mt] * 128 + (k - 128)];
                        a[mt] = pack8(*(const float4*)s, *(const float4*)(s + 4));
                    }
                } else if (MODE == 5) {
                    a[mt] = *(const bf16x8*)&hbuf[grow[mt] * 128 + k];
                } else {  // 7,8: sequential e-stream in CSR space
                    a[mt] = *(const bf16x8*)&ebuf[grow[mt] * 128 + k];
                }
            }
            #pragma unroll
            for (int nt = 0; nt < 4; ++nt)
                b[nt] = *(const bf16x8*)&W1f[(size_t)(((ch * 2 + wn) * 4 + nt) * 512) + lane * 8];
            #pragma unroll
            for (int mt = 0; mt < 4; ++mt)
                #pragma unroll
                for (int nt = 0; nt < 4; ++nt)
                    acc[mt][nt] = __builtin_amdgcn_mfma_f32_16x16x32_bf16(
                                      a[mt], b[nt], acc[mt][nt], 0, 0, 0);
        }
        #pragma unroll
        for (int mt = 0; mt < 4; ++mt)
            #pragma unroll
            for (int nt = 0; nt < 4; ++nt)
                #pragma unroll
                for (int reg = 0; reg < 4; ++reg) {
                    int row = wm * 64 + mt * 16 + lq * 4 + reg;
                    int col = wn * 64 + nt * 16 + lr;
                    float v = acc[mt][nt][reg];
                    if (MODE == 0 || MODE == 2) v = fmaxf(v, 0.f);  // relu now
                    Hs[row * 136 + col] = f2bf(v);
                }
        __syncthreads();
    }

    // ---------------- P fix-up: Hs = relu(base + P_s + P_t) ----------------
    if constexpr (FIX) {
        for (int f = tid; f < 1024; f += TPB) {
            int r = f >> 3, q = f & 7, col = q * 16;
            int s = sIdx[r], t = tIdx[r];
            const u16* ps = &Pbuf[(size_t)s * 256 + col];
            const u16* pt = &Pbuf[(size_t)t * 256 + 128 + col];
            alignas(16) u16 psv[16], ptv[16];
            *(uint4*)&psv[0] = *(const uint4*)&ps[0];
            *(uint4*)&psv[8] = *(const uint4*)&ps[8];
            *(uint4*)&ptv[0] = *(const uint4*)&pt[0];
            *(uint4*)&ptv[8] = *(const uint4*)&pt[8];
            #pragma unroll
            for (int j = 0; j < 16; ++j) {
                float base = (MODE == 6) ? b1s[col + j] : bf2f(Hs[r * 136 + col + j]);
                float v = base + bf2f(psv[j]) + bf2f(ptv[j]);
                Hs[r * 136 + col + j] = f2bf(fmaxf(v, 0.f));
            }
        }
        __syncthreads();
    }

    // ---------------- outputs ----------------
    if constexpr (MODE == 5) {      // raw hidden -> P slice (row stride 256)
        u16* out = (u16*)outp;
        for (int f = tid; f < 1024; f += TPB) {
            int r = f >> 3, q = f & 7, col = q * 16;
            long row = tile0 + r;
            if (row >= NROWS) continue;
            *(uint4*)&out[row * 256 + col]     = *(const uint4*)&Hs[r * 136 + col];
            *(uint4*)&out[row * 256 + col + 8] = *(const uint4*)&Hs[r * 136 + col + 8];
        }
        return;
    }

    if constexpr (HEAD) {           // 128 -> 1; scatter to original edge id
        float s = 0.f;
        int r = tid >> 1, k0 = (tid & 1) * 64;
        #pragma unroll
        for (int j = 0; j < 64; ++j)
            s += bf2f(Hs[r * 136 + k0 + j]) * w2s[k0 + j];
        part[tid] = s;
        __syncthreads();
        if (tid < 128) {
            long row = tile0 + tid;
            if (row < NROWS)
                ((float*)outp)[eidS[tid]] = part[tid * 2] + part[tid * 2 + 1] + bias2[0];
        }
        return;
    }

    if constexpr (MODE == 0 || MODE == 2 || MODE == 6 || MODE == 7) {
        f32x4 acc2[4][4];
        #pragma unroll
        for (int nt = 0; nt < 4; ++nt) {
            float bv = w2orb2[wn * 64 + nt * 16 + lr];
            #pragma unroll
            for (int mt = 0; mt < 4; ++mt) acc2[mt][nt] = (f32x4){bv, bv, bv, bv};
        }
        #pragma unroll
        for (int ch = 0; ch < 4; ++ch) {
            bf16x8 a[4], b[4];
            #pragma unroll
            for (int mt = 0; mt < 4; ++mt)
                a[mt] = *(const bf16x8*)&Hs[(wm * 64 + mt * 16 + lr) * 136 + ch * 32 + lq * 8];
            #pragma unroll
            for (int nt = 0; nt < 4; ++nt)
                b[nt] = *(const bf16x8*)&W2f[(size_t)(((ch * 2 + wn) * 4 + nt) * 512) + lane * 8];
            #pragma unroll
            for (int mt = 0; mt < 4; ++mt)
                #pragma unroll
                for (int nt = 0; nt < 4; ++nt)
                    acc2[mt][nt] = __builtin_amdgcn_mfma_f32_16x16x32_bf16(
                                       a[mt], b[nt], acc2[mt][nt], 0, 0, 0);
        }
        __syncthreads();
        #pragma unroll
        for (int mt = 0; mt < 4; ++mt)
            #pragma unroll
            for (int nt = 0; nt < 4; ++nt)
                #pragma unroll
                for (int reg = 0; reg < 4; ++reg) {
                    int row = wm * 64 + mt * 16 + lq * 4 + reg;
                    int col = wn * 64 + nt * 16 + lr;
                    Hs[row * 136 + col] = f2bf(acc2[mt][nt][reg]);
                }
        __syncthreads();

        u16* out = (u16*)outp;
        for (int f = tid; f < 1024; f += TPB) {
            int r = f >> 3, q = f & 7, col = q * 16;
            long row = tile0 + r;
            if (row >= NROWS) continue;
            const u16* hp = &Hs[r * 136 + col];
            alignas(16) u16 ov[16];
            if (MODE == 2 || MODE == 7) {
                const u16* res = (MODE == 2) ? &hbuf[row * 128 + col] : &ebuf[row * 128 + col];
                #pragma unroll
                for (int j = 0; j < 16; ++j) ov[j] = f2bf(bf2f(hp[j]) + bf2f(res[j]));
            } else {
                #pragma unroll
                for (int j = 0; j < 16; ++j) ov[j] = hp[j];
            }
            *(uint4*)&out[row * 128 + col]     = *(const uint4*)&ov[0];
            *(uint4*)&out[row * 128 + col + 8] = *(const uint4*)&ov[8];
        }
    }
}

// --------------------------- plain kernel symbols ---------------------------

__global__ void k_detect(const int* __restrict__ ei, int* __restrict__ flag) {
    if (threadIdx.x == 0 && blockIdx.x == 0) {
        int any = 0;
        for (int i = 0; i < 64; ++i) any |= ei[2 * i + 1];
        flag[0] = (any == 0) ? 1 : 0;
    }
}

__global__ void k_prep2(const float* __restrict__ W, u16* __restrict__ dst,
                        int nch, int Kreal) {
    int total = nch * 4096;
    for (int i = blockIdx.x * TPB + threadIdx.x; i < total; i += gridDim.x * TPB) {
        int j    = i & 7;
        int lane = (i >> 3) & 63;
        int nt   = (i >> 9) & 3;
        int wnn  = (i >> 11) & 1;
        int ch   = i >> 12;
        int k = ch * 32 + (lane >> 4) * 8 + j;
        int n = wnn * 64 + nt * 16 + (lane & 15);
        dst[i] = f2bf((k < Kreal) ? W[(size_t)k * 128 + n] : 0.f);
    }
}

// ---- CSR build (bucket edges by destination) ----
__global__ void k_hist(const int* __restrict__ ei, const int* __restrict__ flag,
                       int* __restrict__ deg) {
    int i = blockIdx.x * TPB + threadIdx.x;
    if (i < NE) atomicAdd(&deg[load_idx(ei, (long)NE + i, flag[0])], 1);
}
__global__ void k_scanA(const int* __restrict__ deg, int* __restrict__ rp,
                        int* __restrict__ bsum) {
    __shared__ int s[256];
    int t = threadIdx.x, gi = blockIdx.x * 256 + t;
    s[t] = (gi < NN) ? deg[gi] : 0;
    for (int off = 1; off < 256; off <<= 1) {
        __syncthreads();
        int v = (t >= off) ? s[t - off] : 0;
        __syncthreads();
        s[t] += v;
    }
    __syncthreads();
    if (gi < NN) rp[gi] = s[t];
    if (t == 255) bsum[blockIdx.x] = s[255];
}
__global__ void k_scanB(int* __restrict__ bsum, int* __restrict__ boff, int nb) {
    if (threadIdx.x == 0 && blockIdx.x == 0) {
        int run = 0;
        for (int b = 0; b < nb; ++b) { boff[b] = run; run += bsum[b]; }
    }
}
__global__ void k_scanC(const int* __restrict__ deg, int* __restrict__ rp,
                        const int* __restrict__ boff) {
    int t = threadIdx.x, gi = blockIdx.x * 256 + t;
    if (gi >= NN) return;
    int incl = rp[gi] + boff[blockIdx.x];
    rp[gi] = incl - deg[gi];
    if (gi == NN - 1) rp[NN] = incl;
}
__global__ void k_fill(const int* __restrict__ ei, const int* __restrict__ flag,
                       int* __restrict__ cursor, int* __restrict__ eids) {
    int i = blockIdx.x * TPB + threadIdx.x;
    if (i >= NE) return;
    int n = load_idx(ei, (long)NE + i, flag[0]);
    int pos = atomicAdd(&cursor[n], 1);
    eids[pos] = i;
}

// msg[n] = sum of e rows rp[n]..rp[n+1] (e in CSR order: fully sequential)
__global__ void k_gatherS(const u16* __restrict__ e, const int* __restrict__ rp,
                          float* __restrict__ msg) {
    int node = blockIdx.x * 4 + (threadIdx.x >> 6);
    if (node >= NN) return;
    int lane = threadIdx.x & 63;
    int beg = rp[node], end = rp[node + 1];
    float a0 = 0.f, a1 = 0.f;
    for (int i = beg; i < end; ++i) {
        unsigned v = ((const unsigned*)e)[(size_t)i * 64 + lane];
        a0 += bf2f((u16)(v & 0xffff));
        a1 += bf2f((u16)(v >> 16));
    }
    float2 o; o.x = a0; o.y = a1;
    *(float2*)&msg[(size_t)node * 128 + lane * 2] = o;
}

// ---- wrappers ----
__launch_bounds__(TPB)
__global__ void k_node_enc(const float* nodes, const u16* W1f, const float* b1,
                           const u16* W2f, const float* b2, u16* h) {
    mlp_v3<0>(nullptr, nullptr, nodes, nullptr, nullptr, nullptr, nullptr,
              W1f, b1, W2f, b2, nullptr, h);
}
__launch_bounds__(TPB)
__global__ void k_node_upd(const u16* h, const float* msg,
                           const u16* W1f, const float* b1,
                           const u16* W2f, const float* b2, u16* hout) {
    mlp_v3<2>(h, nullptr, msg, nullptr, nullptr, nullptr, nullptr,
              W1f, b1, W2f, b2, nullptr, hout);
}
__launch_bounds__(TPB)
__global__ void k_pcomp(const u16* h, const u16* W1fbase, u16* Pout) {
    const u16* W1f = W1fbase + (size_t)blockIdx.y * (4 * 4096);
    u16* out = Pout + (size_t)blockIdx.y * 128;
    mlp_v3<5>(h, nullptr, nullptr, nullptr, nullptr, nullptr, nullptr,
              W1f, nullptr, nullptr, nullptr, nullptr, out);
}
__launch_bounds__(TPB)
__global__ void k_edge_encP(const u16* P, const int* ei, const int* eids,
                            const int* flag, const float* b1,
                            const u16* W2f, const float* b2, u16* e) {
    mlp_v3<6>(nullptr, nullptr, nullptr, P, ei, eids, flag,
              nullptr, b1, W2f, b2, nullptr, e);
}
__launch_bounds__(TPB)
__global__ void k_edge_updP(const u16* e, const u16* P, const int* ei,
                            const int* eids, const int* flag,
                            const u16* W1fe, const float* b1,
                            const u16* W2f, const float* b2, u16* eout) {
    mlp_v3<7>(nullptr, e, nullptr, P, ei, eids, flag,
              W1fe, b1, W2f, b2, nullptr, eout);
}
__launch_bounds__(TPB)
__global__ void k_decodeP(const u16* e, const u16* P, const int* ei,
                          const int* eids, const int* flag,
                          const u16* W1fe, const float* b1,
                          const float* w2, const float* b2, float* pred) {
    mlp_v3<8>(nullptr, e, nullptr, P, ei, eids, flag,
              W1fe, b1, nullptr, w2, b2, pred);
}

// ---------------------------------------------------------------------------

extern "C" void kernel_launch(void* const* d_in, const int* in_sizes, int n_in,
                              void* d_out, int out_size, void* d_ws, size_t ws_size,
                              hipStream_t stream)
{
    const float* nodes = (const float*)d_in[0];
    const int*   ei    = (const int*)d_in[1];
    const float* ne_W1 = (const float*)d_in[2];  const float* ne_b1 = (const float*)d_in[3];
    const float* ne_W2 = (const float*)d_in[4];  const float* ne_b2 = (const float*)d_in[5];
    const float* ee_W1 = (const float*)d_in[6];  const float* ee_b1 = (const float*)d_in[7];
    const float* ee_W2 = (const float*)d_in[8];  const float* ee_b2 = (const float*)d_in[9];
    const float* nn_W1 = (const float*)d_in[10]; const float* nn_b1 = (const float*)d_in[11];
    const float* nn_W2 = (const float*)d_in[12]; const float* nn_b2 = (const float*)d_in[13];
    const float* en_W1 = (const float*)d_in[14]; const float* en_b1 = (const float*)d_in[15];
    const float* en_W2 = (const float*)d_in[16]; const float* en_b2 = (const float*)d_in[17];
    const float* pe_W1 = (const float*)d_in[18]; const float* pe_b1 = (const float*)d_in[19];
    const float* pe_W2 = (const float*)d_in[20]; const float* pe_b2 = (const float*)d_in[21];

    const size_t hN = (size_t)NN * D;
    const size_t eN = (size_t)NE * D;
    const int NB = (NN + 255) / 256;

    const size_t wTot = (size_t)(32 + 128 + 256 + 128 + 256 + 128 + 384 + 128 + 384) * 128;
    const size_t csrB = (size_t)NN * 4 + (size_t)(NN + 1) * 4 + (size_t)NN * 4
                      + (size_t)NE * 4 + 1024 * 4;
    const size_t shB  = hN * 4;     // shared region: msg fp32 / P bf16
    const size_t need = 256 + hN * 2 * 2 + eN * 2 + shB + (size_t)NE * 4
                      + wTot * 2 + csrB;    // ~262.5 MB (proven fit on R16)

    if (ws_size < need) {
        hipMemsetAsync(d_out, 0x43, (size_t)out_size * sizeof(float), stream);
        return;
    }

    char* p = (char*)d_ws;
    int*   flag = (int*)p;                 p += 256;
    u16*   h0   = (u16*)p;                 p += hN * 2;
    u16*   h1   = (u16*)p;                 p += hN * 2;
    u16*   e    = (u16*)p;                 p += eN * 2;
    char*  shared = p;                     p += shB;     // msg fp32 / P bf16
    float* stage = (float*)p;              p += (size_t)NE * 4;
    u16* wbase = (u16*)p;
    u16* ne1f = wbase;                    u16* ne2f = ne1f + (size_t)32  * 128;
    u16* ee1f = ne2f + (size_t)128 * 128; u16* ee2f = ee1f + (size_t)256 * 128;
    u16* nn1f = ee2f + (size_t)128 * 128; u16* nn2f = nn1f + (size_t)256 * 128;
    u16* en1f = nn2f + (size_t)128 * 128; u16* en2f = en1f + (size_t)384 * 128;
    u16* pe1f = en2f + (size_t)128 * 128;
    p = (char*)(pe1f + (size_t)384 * 128);
    int* deg  = (int*)p;                   p += (size_t)NN * 4;
    int* rp   = (int*)p;                   p += (size_t)(NN + 1) * 4;
    int* cur  = (int*)p;                   p += (size_t)NN * 4;
    int* eids = (int*)p;                   p += (size_t)NE * 4;
    int* bsum = (int*)p;                   p += 512 * 4;
    int* boff = (int*)p;

    float* msg = (float*)shared;
    u16*   P   = (u16*)shared;

    dim3 blk(TPB);
    k_detect<<<1, 64, 0, stream>>>(ei, flag);

    k_prep2<<<32, blk, 0, stream>>>(ne_W1, ne1f, 1, 16);
    k_prep2<<<32, blk, 0, stream>>>(ne_W2, ne2f, 4, 128);
    k_prep2<<<32, blk, 0, stream>>>(ee_W1, ee1f, 8, 256);
    k_prep2<<<32, blk, 0, stream>>>(ee_W2, ee2f, 4, 128);
    k_prep2<<<32, blk, 0, stream>>>(nn_W1, nn1f, 8, 256);
    k_prep2<<<32, blk, 0, stream>>>(nn_W2, nn2f, 4, 128);
    k_prep2<<<32, blk, 0, stream>>>(en_W1, en1f, 12, 384);
    k_prep2<<<32, blk, 0, stream>>>(en_W2, en2f, 4, 128);
    k_prep2<<<32, blk, 0, stream>>>(pe_W1, pe1f, 12, 384);

    // CSR build: rp (row ptr by destination), eids (CSR pos -> orig edge id)
    hipMemsetAsync(deg, 0, (size_t)NN * 4, stream);
    k_hist<<<(NE + TPB - 1) / TPB, blk, 0, stream>>>(ei, flag, deg);
    k_scanA<<<NB, blk, 0, stream>>>(deg, rp, bsum);
    k_scanB<<<1, 64, 0, stream>>>(bsum, boff, NB);
    k_scanC<<<NB, blk, 0, stream>>>(deg, rp, boff);
    hipMemcpyAsync(cur, rp, (size_t)NN * 4, hipMemcpyDeviceToDevice, stream);
    k_fill<<<(NE + TPB - 1) / TPB, blk, 0, stream>>>(ei, flag, cur, eids);

    const int EG = (NE + 127) / 128;    // 4688 CSR-position tiles
    const int NG = (NN + 127) / 128;    // 782
    dim3 pg(NG, 2);

    k_node_enc<<<NG, blk, 0, stream>>>(nodes, ne1f, ne_b1, ne2f, ne_b2, h0);

    // e (CSR order) = edge_enc via P
    k_pcomp<<<pg, blk, 0, stream>>>(h0, ee1f, P);
    k_edge_encP<<<EG, blk, 0, stream>>>(P, ei, eids, flag, ee_b1, ee2f, ee_b2, e);

    u16* hOld = h0; u16* hNew = h1;
    for (int it = 0; it < 4; ++it) {
        // msg = segment-sum of e (sequential read; e already dest-sorted)
        k_gatherS<<<(NN + 3) / 4, blk, 0, stream>>>(e, rp, msg);
        // h_new <- MLP_nn([h_old, msg]) + h_old    (msg dead after this)
        k_node_upd<<<NG, blk, 0, stream>>>(hOld, msg, nn1f, nn_b1, nn2f, nn_b2, hNew);
        // P <- h_old @ en_W1[s|t]                  (overwrites msg region)
        k_pcomp<<<pg, blk, 0, stream>>>(hOld, en1f, P);
        // e <- MLP_en(P_s + P_t + e@W1_e + b1) + e (CSR order preserved)
        k_edge_updP<<<EG, blk, 0, stream>>>(e, P, ei, eids, flag,
                                            en1f + 8 * 4096, en_b1, en2f, en_b2, e);
        u16* t = hOld; hOld = hNew; hNew = t;
    }

    k_pcomp<<<pg, blk, 0, stream>>>(hOld, pe1f, P);
    k_decodeP<<<EG, blk, 0, stream>>>(e, P, ei, eids, flag,
                                      pe1f + 8 * 4096, pe_b1, pe_W2, pe_b2, stage);
    hipMemcpyAsync(d_out, stage, (size_t)NE * sizeof(float),
                   hipMemcpyDeviceToDevice, stream);
}